// Round 7
// baseline (428.562 us; speedup 1.0000x reference)
//
#include <hip/hip_runtime.h>
#include <hip/hip_fp16.h>
#include <math.h>

#define NEG_SLOPE 0.2f
#define LOG2E 1.44269504088896f

#if __has_builtin(__builtin_amdgcn_exp2f)
#define EXP2(x) __builtin_amdgcn_exp2f(x)
#else
#define EXP2(x) exp2f(x)
#endif

typedef _Float16 half8 __attribute__((ext_vector_type(8)));
typedef float floatx4 __attribute__((ext_vector_type(4)));

// ---------------- pack W1 [128][256] fp32 -> f16 B-fragment order ----------------
__global__ __launch_bounds__(256) void pack_W1(const float* __restrict__ W1,
                                               half8* __restrict__ Bpack) {
  int tid = blockIdx.x * 256 + threadIdx.x;  // 4096 total
  int l = tid & 63;
  int ksnt = tid >> 6;
  int ks = ksnt & 3;
  int nt = ksnt >> 2;
  int col = nt * 16 + (l & 15);
  int krow = ks * 32 + (l >> 4) * 8;
  half8 v;
#pragma unroll
  for (int j = 0; j < 8; j++) v[j] = (_Float16)W1[(krow + j) * 256 + col];
  Bpack[tid] = v;
}

// ---------------- Kernel A: h1t = x @ W1 via MFMA (group-sharded layout) ----------
// h1t[g][node][32] fp16 where g = ch>>5. a1s/a1d stored fp16, PRE-SCALED by log2e.
__global__ __launch_bounds__(256) void gemm1_mfma(
    const float* __restrict__ x, const half8* __restrict__ Bpack,
    const float* __restrict__ att_s, const float* __restrict__ att_d,
    __half* __restrict__ h1t, __half* __restrict__ a1s, __half* __restrict__ a1d,
    int N) {
  const int wave = threadIdx.x >> 6, lane = threadIdx.x & 63;
  const int quad = lane >> 4, li = lane & 15;
  const int n0 = (blockIdx.x * 4 + wave) * 16;
  if (n0 >= N) return;
  floatx4 acc[16];
#pragma unroll
  for (int t = 0; t < 16; t++) acc[t] = (floatx4){0.f, 0.f, 0.f, 0.f};
  const float* xrow = x + (size_t)(n0 + li) * 128;
#pragma unroll
  for (int ks = 0; ks < 4; ks++) {
    float4 xa = *(const float4*)(xrow + ks * 32 + quad * 8);
    float4 xb = *(const float4*)(xrow + ks * 32 + quad * 8 + 4);
    half8 a;
    a[0] = (_Float16)xa.x; a[1] = (_Float16)xa.y;
    a[2] = (_Float16)xa.z; a[3] = (_Float16)xa.w;
    a[4] = (_Float16)xb.x; a[5] = (_Float16)xb.y;
    a[6] = (_Float16)xb.z; a[7] = (_Float16)xb.w;
#pragma unroll
    for (int nt = 0; nt < 16; nt++) {
      half8 b = Bpack[(nt * 4 + ks) * 64 + lane];
      acc[nt] = __builtin_amdgcn_mfma_f32_16x16x32_f16(a, b, acc[nt], 0, 0, 0);
    }
  }
  // store h1t: ch = nt*16+li -> g = nt>>1, within = (nt&1)*16+li
#pragma unroll
  for (int nt = 0; nt < 16; nt++) {
#pragma unroll
    for (int r = 0; r < 4; r++) {
      int node = n0 + quad * 4 + r;
      size_t pos = ((size_t)(nt >> 1) * N + node) * 32 + (nt & 1) * 16 + li;
      h1t[pos] = __float2half(acc[nt][r]);
    }
  }
  // fused attention dots: channel ch = nt*16+li, head = nt>>2
  float as_f[16], ad_f[16];
#pragma unroll
  for (int nt = 0; nt < 16; nt++) {
    as_f[nt] = att_s[nt * 16 + li];
    ad_f[nt] = att_d[nt * 16 + li];
  }
#pragma unroll
  for (int r = 0; r < 4; r++) {
    int node = n0 + quad * 4 + r;
#pragma unroll
    for (int h = 0; h < 4; h++) {
      float vs = 0.f, vd = 0.f;
#pragma unroll
      for (int ntl = 0; ntl < 4; ntl++) {
        int nt = h * 4 + ntl;
        vs = fmaf(acc[nt][r], as_f[nt], vs);
        vd = fmaf(acc[nt][r], ad_f[nt], vd);
      }
#pragma unroll
      for (int off = 8; off > 0; off >>= 1) {
        vs += __shfl_down(vs, off, 16);
        vd += __shfl_down(vd, off, 16);
      }
      if (li == 0) {
        a1s[node * 4 + h] = __float2half(vs * LOG2E);
        a1d[node * 4 + h] = __float2half(vd * LOG2E);
      }
    }
  }
}

// ---------------- CSR build (self-loops placed analytically) ----------------
__global__ void hist_deg(const int* __restrict__ dst, int* __restrict__ deg, int E) {
  int e = blockIdx.x * 256 + threadIdx.x;
  if (e >= E) return;
  atomicAdd(deg + dst[e], 1);
}

__global__ void scan_local(const int* __restrict__ deg, int* __restrict__ excl,
                           int* __restrict__ bsum, int N) {
  __shared__ int s[256];
  int i = blockIdx.x * 256 + threadIdx.x;
  int v = (i < N) ? deg[i] + 1 : 0;  // +1 = self-loop
  s[threadIdx.x] = v;
  __syncthreads();
  for (int off = 1; off < 256; off <<= 1) {
    int t = (threadIdx.x >= off) ? s[threadIdx.x - off] : 0;
    __syncthreads();
    s[threadIdx.x] += t;
    __syncthreads();
  }
  if (i < N) excl[i] = s[threadIdx.x] - v;
  if (threadIdx.x == 255) bsum[blockIdx.x] = s[255];
}

__global__ void scan_bsum(int* __restrict__ bsum, int nb) {
  __shared__ int s[256];
  int v = (threadIdx.x < nb) ? bsum[threadIdx.x] : 0;
  s[threadIdx.x] = v;
  __syncthreads();
  for (int off = 1; off < 256; off <<= 1) {
    int t = (threadIdx.x >= off) ? s[threadIdx.x - off] : 0;
    __syncthreads();
    s[threadIdx.x] += t;
    __syncthreads();
  }
  if (threadIdx.x < nb) bsum[threadIdx.x] = s[threadIdx.x] - v;  // exclusive
}

__global__ void scan_add(const int* __restrict__ excl, const int* __restrict__ bsum,
                         int* __restrict__ rowptr, int* __restrict__ cursor,
                         int* __restrict__ elist, int N, int ET) {
  int i = blockIdx.x * 256 + threadIdx.x;
  if (i < N) {
    int r = excl[i] + bsum[blockIdx.x];
    rowptr[i] = r;
    elist[r] = i;        // self-loop edge placed first
    cursor[i] = r + 1;
  }
  if (i == 0) rowptr[N] = ET;
}

__global__ void scatter_edges(const int* __restrict__ src, const int* __restrict__ dst,
                              int* __restrict__ cursor, int* __restrict__ elist, int E) {
  int e = blockIdx.x * 256 + threadIdx.x;
  if (e >= E) return;
  int pos = atomicAdd(cursor + dst[e], 1);
  elist[pos] = src[e];
}

// ---------------- Kernel C: XCD-sharded channel-slice aggregate ----------------
// group g = blockIdx & 7 (round-robin -> one group per XCD; slice fits 4MB L2).
// wave per node: 4 edge slots x 16 lanes (half2 = 2 channels each).
// Writes out1h[n][256] fp16 = ELU(norm + bias) for layer-2 GEMM.
__global__ __launch_bounds__(256) void agg1_sharded(
    const int* __restrict__ rowptr, const int* __restrict__ elist,
    const __half* __restrict__ h1t, const __half* __restrict__ a1s,
    const __half* __restrict__ a1d, const float* __restrict__ b1,
    __half* __restrict__ out1h, int N) {
  const int g = blockIdx.x & 7;
  const int chunk = blockIdx.x >> 3;
  const int wave = threadIdx.x >> 6, lane = threadIdx.x & 63;
  const int slot = lane >> 4, lp = lane & 15;
  const int n = chunk * 4 + wave;
  if (n >= N) return;
  const int row = rowptr[n];
  const int deg = rowptr[n + 1] - row;
  const int* el = elist + row;
  const int head = g >> 1;
  const float adh = __half2float(a1d[n * 4 + head]);  // pre-scaled by log2e
  const __half* hbase = h1t + (size_t)g * N * 32 + lp * 2;

  float accx = 0.f, accy = 0.f, den = 0.f;
  int j0 = 0;
  for (; j0 + 8 <= deg; j0 += 8) {  // fully-active double quad: 8 edges in flight
    int sA = el[j0 + slot];
    int sB = el[j0 + 4 + slot];
    float lA = __half2float(a1s[sA * 4 + head]) + adh;
    float lB = __half2float(a1s[sB * 4 + head]) + adh;
    __half2 hA = *(const __half2*)(hbase + (size_t)sA * 32);
    __half2 hB = *(const __half2*)(hbase + (size_t)sB * 32);
    float eA = EXP2(fmaxf(lA, NEG_SLOPE * lA));
    float eB = EXP2(fmaxf(lB, NEG_SLOPE * lB));
    den += eA + eB;
    float2 fA = __half22float2(hA);
    float2 fB = __half22float2(hB);
    accx = fmaf(eA, fA.x, fmaf(eB, fB.x, accx));
    accy = fmaf(eA, fA.y, fmaf(eB, fB.y, accy));
  }
  for (; j0 < deg; j0 += 4) {  // predicated tail
    int jj = j0 + slot;
    bool act = jj < deg;
    int s = act ? el[jj] : el[0];
    float l = __half2float(a1s[s * 4 + head]) + adh;
    __half2 hv = *(const __half2*)(hbase + (size_t)s * 32);
    float e = act ? EXP2(fmaxf(l, NEG_SLOPE * l)) : 0.f;
    den += e;
    float2 f = __half22float2(hv);
    accx = fmaf(e, f.x, accx);
    accy = fmaf(e, f.y, accy);
  }
  // reduce across the 4 slots
  accx += __shfl_xor(accx, 16, 64); accx += __shfl_xor(accx, 32, 64);
  accy += __shfl_xor(accy, 16, 64); accy += __shfl_xor(accy, 32, 64);
  den  += __shfl_xor(den, 16, 64);  den  += __shfl_xor(den, 32, 64);
  float inv = 1.0f / den;
  int ch = g * 32 + lp * 2;
  float c0 = fmaf(accx, inv, b1[ch]);
  float c1 = fmaf(accy, inv, b1[ch + 1]);
  c0 = c0 > 0.f ? c0 : expm1f(c0);
  c1 = c1 > 0.f ? c1 : expm1f(c1);
  if (slot == 0) {
    __half2 o;
    o.x = __float2half(c0);
    o.y = __float2half(c1);
    *(__half2*)(out1h + (size_t)n * 256 + ch) = o;
  }
}

// ---------------- Kernel D: GEMM2 from out1h + layer-2 attention dots -------------
__global__ __launch_bounds__(256) void layer2_prep(
    const __half* __restrict__ out1h, const float* __restrict__ W2,
    const float* __restrict__ as2, const float* __restrict__ ad2,
    __half* __restrict__ h2, float* __restrict__ a2s, float* __restrict__ a2d,
    int N) {
  __shared__ float w2s[64 * 41];  // lane-stride 41 -> conflict-free
  const int t = threadIdx.x;
  for (int i = t; i < 2560; i += 256) {
    int ch = i / 10, jj = i - ch * 10;
    w2s[(ch >> 2) * 41 + (ch & 3) * 10 + jj] = W2[i];
  }
  __syncthreads();
  const int wave = t >> 6, lane = t & 63;
  const int n = blockIdx.x * 4 + wave;
  if (n >= N) return;
  uint2 u = *(const uint2*)(out1h + (size_t)n * 256 + lane * 4);
  float2 ab = __half22float2(*(const __half2*)&u.x);
  float2 cd = __half22float2(*(const __half2*)&u.y);
  const float* w0 = w2s + lane * 41;
  float p[10];
#pragma unroll
  for (int jj = 0; jj < 10; jj++)
    p[jj] = fmaf(ab.x, w0[jj],
            fmaf(ab.y, w0[10 + jj], fmaf(cd.x, w0[20 + jj], cd.y * w0[30 + jj])));
#pragma unroll
  for (int jj = 0; jj < 10; jj++) {
#pragma unroll
    for (int off = 32; off > 0; off >>= 1) p[jj] += __shfl_down(p[jj], off, 64);
  }
  if (lane == 0) {
    float ds = 0.f, dd = 0.f;
#pragma unroll
    for (int jj = 0; jj < 10; jj++) {
      h2[(size_t)n * 16 + jj] = __float2half(p[jj]);
      ds = fmaf(p[jj], as2[jj], ds);
      dd = fmaf(p[jj], ad2[jj], dd);
    }
    a2s[n] = ds * LOG2E;
    a2d[n] = dd * LOG2E;
  }
}

// ---------------- Kernel F: wave-per-node layer-2 aggregate, fast-exp softmax ------
__global__ __launch_bounds__(256) void agg2_csr(
    const int* __restrict__ rowptr, const int* __restrict__ elist,
    const __half* __restrict__ h2, const float* __restrict__ a2s,
    const float* __restrict__ a2d, const float* __restrict__ b2,
    float* __restrict__ out, int N) {
  int wave = threadIdx.x >> 6, lane = threadIdx.x & 63;
  int n = blockIdx.x * 4 + wave;
  if (n >= N) return;
  int row = rowptr[n];
  int deg = rowptr[n + 1] - row;
  const int* el = elist + row;
  float ad = a2d[n];  // pre-scaled
  int g = lane / 10;  // 0..5 active, lanes 60-63 idle
  int c = lane - g * 10;
  float den = 0.f, acc = 0.f;
  if (g < 6) {
    for (int jj = g; jj < deg; jj += 6) {
      int s = el[jj];
      float l = a2s[s] + ad;
      float ev = EXP2(fmaxf(l, NEG_SLOPE * l));
      den += ev;
      acc = fmaf(ev, __half2float(h2[(size_t)s * 16 + c]), acc);
    }
  }
  acc += __shfl_down(acc, 30, 64);
  den += __shfl_down(den, 30, 64);
  acc += __shfl_down(acc, 10, 64) + __shfl_down(acc, 20, 64);
  den += __shfl_down(den, 10, 64) + __shfl_down(den, 20, 64);
  if (lane < 10) out[(size_t)n * 10 + lane] = acc / den + b2[lane];
}

extern "C" void kernel_launch(void* const* d_in, const int* in_sizes, int n_in,
                              void* d_out, int out_size, void* d_ws, size_t ws_size,
                              hipStream_t stream) {
  const float* x = (const float*)d_in[0];
  const int* ei = (const int*)d_in[1];
  const float* W1 = (const float*)d_in[2];
  const float* as1 = (const float*)d_in[3];
  const float* ad1 = (const float*)d_in[4];
  const float* b1 = (const float*)d_in[5];
  const float* W2 = (const float*)d_in[6];
  const float* as2 = (const float*)d_in[7];
  const float* ad2 = (const float*)d_in[8];
  const float* b2 = (const float*)d_in[9];
  float* out = (float*)d_out;

  const int N = in_sizes[0] / 128;   // 50000
  const int E = in_sizes[1] / 2;     // 800000
  const int ET = E + N;
  const int* srcp = ei;
  const int* dstp = ei + E;

  char* ws = (char*)d_ws;
  size_t off = 0;
  auto alloc = [&](size_t nbytes) {
    char* p = ws + off;
    off += (nbytes + 255) & ~(size_t)255;
    return p;
  };
  __half* h1t = (__half*)alloc((size_t)N * 256 * 2);
  __half* out1h = (__half*)alloc((size_t)N * 256 * 2);
  half8* Bpack = (half8*)alloc((size_t)4096 * 16);
  __half* a1s = (__half*)alloc((size_t)N * 4 * 2);
  __half* a1d = (__half*)alloc((size_t)N * 4 * 2);
  __half* h2 = (__half*)alloc((size_t)N * 16 * 2);
  float* a2sv = (float*)alloc((size_t)N * 4);
  float* a2dv = (float*)alloc((size_t)N * 4);
  int* deg = (int*)alloc((size_t)N * 4);
  int* excl = (int*)alloc((size_t)N * 4);
  int* bsum = (int*)alloc(256 * 4);
  int* rowptr = (int*)alloc((size_t)(N + 1) * 4);
  int* cursor = (int*)alloc((size_t)N * 4);
  int* elist = (int*)alloc((size_t)ET * 4);

  const int nb = (N + 255) / 256;

  hipMemsetAsync(deg, 0, (size_t)N * 4, stream);

  // CSR build (self-loops analytic)
  hist_deg<<<(E + 255) / 256, 256, 0, stream>>>(dstp, deg, E);
  scan_local<<<nb, 256, 0, stream>>>(deg, excl, bsum, N);
  scan_bsum<<<1, 256, 0, stream>>>(bsum, nb);
  scan_add<<<nb, 256, 0, stream>>>(excl, bsum, rowptr, cursor, elist, N, ET);
  scatter_edges<<<(E + 255) / 256, 256, 0, stream>>>(srcp, dstp, cursor, elist, E);

  // layer 1: MFMA GEMM with fused attention dots (group-sharded h1t)
  pack_W1<<<16, 256, 0, stream>>>(W1, Bpack);
  gemm1_mfma<<<(N / 16 + 3) / 4, 256, 0, stream>>>(x, Bpack, as1, ad1, h1t, a1s, a1d, N);

  // aggregate layer 1: 8 channel-groups, round-robin -> one group per XCD
  agg1_sharded<<<((N + 3) / 4) * 8, 256, 0, stream>>>(rowptr, elist, h1t, a1s, a1d,
                                                      b1, out1h, N);
  // GEMM2 + att2 dots
  layer2_prep<<<(N + 3) / 4, 256, 0, stream>>>(out1h, W2, as2, ad2, h2, a2sv, a2dv, N);
  // layer 2
  agg2_csr<<<(N + 3) / 4, 256, 0, stream>>>(rowptr, elist, h2, a2sv, a2dv, b2, out, N);
}

// Round 8
// 295.873 us; speedup vs baseline: 1.4485x; 1.4485x over previous
//
#include <hip/hip_runtime.h>
#include <hip/hip_fp16.h>
#include <math.h>

#define NEG_SLOPE 0.2f
#define LOG2E 1.44269504088896f

#if __has_builtin(__builtin_amdgcn_exp2f)
#define EXP2(x) __builtin_amdgcn_exp2f(x)
#else
#define EXP2(x) exp2f(x)
#endif

typedef _Float16 half8 __attribute__((ext_vector_type(8)));
typedef float floatx4 __attribute__((ext_vector_type(4)));

// ---------------- L1: pack W1 (blocks 0..15) + zero deg (blocks 16..) ----------------
__global__ __launch_bounds__(256) void prep1(const float* __restrict__ W1,
                                             half8* __restrict__ Bpack,
                                             int* __restrict__ deg, int N) {
  if (blockIdx.x < 16) {
    int tid = blockIdx.x * 256 + threadIdx.x;  // 4096 total
    int l = tid & 63;
    int ksnt = tid >> 6;
    int ks = ksnt & 3;
    int nt = ksnt >> 2;
    int col = nt * 16 + (l & 15);
    int krow = ks * 32 + (l >> 4) * 8;
    half8 v;
#pragma unroll
    for (int j = 0; j < 8; j++) v[j] = (_Float16)W1[(krow + j) * 256 + col];
    Bpack[tid] = v;
  } else {
    int i = (blockIdx.x - 16) * 256 + threadIdx.x;
    if (i < N) deg[i] = 0;
  }
}

// ---------------- L2: gemm1 MFMA (+fused att dots) ∥ hist_deg ----------------
// h1 linear [n][256] fp16; a1s/a1d fp32 PRE-SCALED by log2e.
__global__ __launch_bounds__(256) void phase2(
    const float* __restrict__ x, const half8* __restrict__ Bpack,
    const float* __restrict__ att_s, const float* __restrict__ att_d,
    __half* __restrict__ h1, float* __restrict__ a1s, float* __restrict__ a1d,
    const int* __restrict__ dst, int* __restrict__ deg,
    int N, int E, int gemmBlocks, int histBlocks) {
  if ((int)blockIdx.x >= gemmBlocks) {
    int b = blockIdx.x - gemmBlocks;
    for (int e = b * 256 + threadIdx.x; e < E; e += histBlocks * 256)
      atomicAdd(deg + dst[e], 1);
    return;
  }
  const int wave = threadIdx.x >> 6, lane = threadIdx.x & 63;
  const int quad = lane >> 4, li = lane & 15;
  const int n0 = (blockIdx.x * 4 + wave) * 16;
  if (n0 >= N) return;
  floatx4 acc[16];
#pragma unroll
  for (int t = 0; t < 16; t++) acc[t] = (floatx4){0.f, 0.f, 0.f, 0.f};
  const float* xrow = x + (size_t)(n0 + li) * 128;
#pragma unroll
  for (int ks = 0; ks < 4; ks++) {
    float4 xa = *(const float4*)(xrow + ks * 32 + quad * 8);
    float4 xb = *(const float4*)(xrow + ks * 32 + quad * 8 + 4);
    half8 a;
    a[0] = (_Float16)xa.x; a[1] = (_Float16)xa.y;
    a[2] = (_Float16)xa.z; a[3] = (_Float16)xa.w;
    a[4] = (_Float16)xb.x; a[5] = (_Float16)xb.y;
    a[6] = (_Float16)xb.z; a[7] = (_Float16)xb.w;
#pragma unroll
    for (int nt = 0; nt < 16; nt++) {
      half8 b = Bpack[(nt * 4 + ks) * 64 + lane];
      acc[nt] = __builtin_amdgcn_mfma_f32_16x16x32_f16(a, b, acc[nt], 0, 0, 0);
    }
  }
#pragma unroll
  for (int nt = 0; nt < 16; nt++) {
#pragma unroll
    for (int r = 0; r < 4; r++) {
      h1[(size_t)(n0 + quad * 4 + r) * 256 + nt * 16 + li] = __float2half(acc[nt][r]);
    }
  }
  float as_f[16], ad_f[16];
#pragma unroll
  for (int nt = 0; nt < 16; nt++) {
    as_f[nt] = att_s[nt * 16 + li];
    ad_f[nt] = att_d[nt * 16 + li];
  }
#pragma unroll
  for (int r = 0; r < 4; r++) {
    int node = n0 + quad * 4 + r;
#pragma unroll
    for (int h = 0; h < 4; h++) {
      float vs = 0.f, vd = 0.f;
#pragma unroll
      for (int ntl = 0; ntl < 4; ntl++) {
        int nt = h * 4 + ntl;
        vs = fmaf(acc[nt][r], as_f[nt], vs);
        vd = fmaf(acc[nt][r], ad_f[nt], vd);
      }
#pragma unroll
      for (int off = 8; off > 0; off >>= 1) {
        vs += __shfl_down(vs, off, 16);
        vd += __shfl_down(vd, off, 16);
      }
      if (li == 0) {
        a1s[node * 4 + h] = vs * LOG2E;
        a1d[node * 4 + h] = vd * LOG2E;
      }
    }
  }
}

// ---------------- CSR scan chain ----------------
__global__ void scan_local(const int* __restrict__ deg, int* __restrict__ excl,
                           int* __restrict__ bsum, int N) {
  __shared__ int s[256];
  int i = blockIdx.x * 256 + threadIdx.x;
  int v = (i < N) ? deg[i] + 1 : 0;  // +1 = self-loop
  s[threadIdx.x] = v;
  __syncthreads();
  for (int off = 1; off < 256; off <<= 1) {
    int t = (threadIdx.x >= off) ? s[threadIdx.x - off] : 0;
    __syncthreads();
    s[threadIdx.x] += t;
    __syncthreads();
  }
  if (i < N) excl[i] = s[threadIdx.x] - v;
  if (threadIdx.x == 255) bsum[blockIdx.x] = s[255];
}

__global__ void scan_bsum(int* __restrict__ bsum, int nb) {
  __shared__ int s[256];
  int v = (threadIdx.x < nb) ? bsum[threadIdx.x] : 0;
  s[threadIdx.x] = v;
  __syncthreads();
  for (int off = 1; off < 256; off <<= 1) {
    int t = (threadIdx.x >= off) ? s[threadIdx.x - off] : 0;
    __syncthreads();
    s[threadIdx.x] += t;
    __syncthreads();
  }
  if (threadIdx.x < nb) bsum[threadIdx.x] = s[threadIdx.x] - v;  // exclusive
}

__global__ void scan_add(const int* __restrict__ excl, const int* __restrict__ bsum,
                         int* __restrict__ rowptr, int* __restrict__ cursor,
                         int* __restrict__ elist, int N, int ET) {
  int i = blockIdx.x * 256 + threadIdx.x;
  if (i < N) {
    int r = excl[i] + bsum[blockIdx.x];
    rowptr[i] = r;
    elist[r] = i;        // self-loop edge placed first
    cursor[i] = r + 1;
  }
  if (i == 0) rowptr[N] = ET;
}

__global__ void scatter_edges(const int* __restrict__ src, const int* __restrict__ dst,
                              int* __restrict__ cursor, int* __restrict__ elist, int E) {
  int e = blockIdx.x * 256 + threadIdx.x;
  if (e >= E) return;
  int pos = atomicAdd(cursor + dst[e], 1);
  elist[pos] = src[e];
}

// ---------------- agg1: wave-per-node CSR aggregate (unroll-8), inline fast-exp
// softmax + bias1 + ELU + GEMM2 (W2 in LDS, stride 41) + layer-2 att dots ----------
__global__ __launch_bounds__(256) void agg1_fused(
    const int* __restrict__ rowptr, const int* __restrict__ elist,
    const __half* __restrict__ h1, const float* __restrict__ a1s,
    const float* __restrict__ a1d, const float* __restrict__ b1,
    const float* __restrict__ W2, const float* __restrict__ as2,
    const float* __restrict__ ad2, __half* __restrict__ h2,
    float* __restrict__ a2s, float* __restrict__ a2d, int N) {
  __shared__ float w2s[64 * 41];  // lane-stride 41 -> conflict-free
  const int t = threadIdx.x;
  for (int i = t; i < 2560; i += 256) {
    int ch = i / 10, jj = i - ch * 10;
    w2s[(ch >> 2) * 41 + (ch & 3) * 10 + jj] = W2[i];
  }
  __syncthreads();

  const int wave = t >> 6, lane = t & 63;
  const int n = blockIdx.x * 4 + wave;
  if (n >= N) return;
  const int row = rowptr[n];
  const int deg = rowptr[n + 1] - row;
  const int* el = elist + row;
  const int hidx = lane >> 4;
  const float adh = a1d[n * 4 + hidx];  // pre-scaled by log2e

  float den = 0.f;
  float acc0 = 0.f, acc1 = 0.f, acc2 = 0.f, acc3 = 0.f;
  int j = 0;
  for (; j + 8 <= deg; j += 8) {
    int ss[8];
#pragma unroll
    for (int u = 0; u < 8; u++) ss[u] = el[j + u];
    float lv[8];
    uint2 uv[8];
#pragma unroll
    for (int u = 0; u < 8; u++) {
      lv[u] = a1s[ss[u] * 4 + hidx];
      uv[u] = *(const uint2*)(h1 + (size_t)ss[u] * 256 + lane * 4);
    }
#pragma unroll
    for (int u = 0; u < 8; u++) {
      float l = lv[u] + adh;
      float e = EXP2(fmaxf(l, NEG_SLOPE * l));
      den += e;
      float2 a = __half22float2(*(const __half2*)&uv[u].x);
      float2 b = __half22float2(*(const __half2*)&uv[u].y);
      acc0 = fmaf(e, a.x, acc0); acc1 = fmaf(e, a.y, acc1);
      acc2 = fmaf(e, b.x, acc2); acc3 = fmaf(e, b.y, acc3);
    }
  }
  for (; j + 4 <= deg; j += 4) {
    int ss[4];
#pragma unroll
    for (int u = 0; u < 4; u++) ss[u] = el[j + u];
    float lv[4];
    uint2 uv[4];
#pragma unroll
    for (int u = 0; u < 4; u++) {
      lv[u] = a1s[ss[u] * 4 + hidx];
      uv[u] = *(const uint2*)(h1 + (size_t)ss[u] * 256 + lane * 4);
    }
#pragma unroll
    for (int u = 0; u < 4; u++) {
      float l = lv[u] + adh;
      float e = EXP2(fmaxf(l, NEG_SLOPE * l));
      den += e;
      float2 a = __half22float2(*(const __half2*)&uv[u].x);
      float2 b = __half22float2(*(const __half2*)&uv[u].y);
      acc0 = fmaf(e, a.x, acc0); acc1 = fmaf(e, a.y, acc1);
      acc2 = fmaf(e, b.x, acc2); acc3 = fmaf(e, b.y, acc3);
    }
  }
  for (; j < deg; j++) {
    int s0 = el[j];
    float l0 = a1s[s0 * 4 + hidx] + adh;
    uint2 u0 = *(const uint2*)(h1 + (size_t)s0 * 256 + lane * 4);
    float e0 = EXP2(fmaxf(l0, NEG_SLOPE * l0));
    den += e0;
    float2 a = __half22float2(*(const __half2*)&u0.x);
    float2 b = __half22float2(*(const __half2*)&u0.y);
    acc0 = fmaf(e0, a.x, acc0); acc1 = fmaf(e0, a.y, acc1);
    acc2 = fmaf(e0, b.x, acc2); acc3 = fmaf(e0, b.y, acc3);
  }

  // epilogue: normalize + bias + ELU ; p[10] = sum_k c_k * W2[c_k][:] ; wave-reduce
  float inv = 1.0f / den;
  float4 bb = *(const float4*)(b1 + lane * 4);
  float c0 = fmaf(acc0, inv, bb.x);
  float c1 = fmaf(acc1, inv, bb.y);
  float c2 = fmaf(acc2, inv, bb.z);
  float c3 = fmaf(acc3, inv, bb.w);
  c0 = c0 > 0.f ? c0 : expm1f(c0);
  c1 = c1 > 0.f ? c1 : expm1f(c1);
  c2 = c2 > 0.f ? c2 : expm1f(c2);
  c3 = c3 > 0.f ? c3 : expm1f(c3);
  const float* w0 = w2s + lane * 41;
  float p[10];
#pragma unroll
  for (int jj = 0; jj < 10; jj++)
    p[jj] = fmaf(c0, w0[jj], fmaf(c1, w0[10 + jj], fmaf(c2, w0[20 + jj], c3 * w0[30 + jj])));
#pragma unroll
  for (int jj = 0; jj < 10; jj++) {
#pragma unroll
    for (int off = 32; off > 0; off >>= 1) p[jj] += __shfl_down(p[jj], off, 64);
  }
  if (lane == 0) {
    float ds = 0.f, dd = 0.f;
#pragma unroll
    for (int jj = 0; jj < 10; jj++) {
      h2[(size_t)n * 16 + jj] = __float2half(p[jj]);
      ds = fmaf(p[jj], as2[jj], ds);
      dd = fmaf(p[jj], ad2[jj], dd);
    }
    a2s[n] = ds * LOG2E;
    a2d[n] = dd * LOG2E;
  }
}

// ---------------- agg2: wave-per-node layer-2 aggregate, fast-exp, unroll-2 --------
__global__ __launch_bounds__(256) void agg2_csr(
    const int* __restrict__ rowptr, const int* __restrict__ elist,
    const __half* __restrict__ h2, const float* __restrict__ a2s,
    const float* __restrict__ a2d, const float* __restrict__ b2,
    float* __restrict__ out, int N) {
  int wave = threadIdx.x >> 6, lane = threadIdx.x & 63;
  int n = blockIdx.x * 4 + wave;
  if (n >= N) return;
  int row = rowptr[n];
  int deg = rowptr[n + 1] - row;
  const int* el = elist + row;
  float ad = a2d[n];  // pre-scaled
  int g = lane / 10;  // 0..5 active, lanes 60-63 idle
  int c = lane - g * 10;
  float den = 0.f, acc = 0.f;
  if (g < 6) {
    int jj = g;
    for (; jj + 6 < deg; jj += 12) {
      int sA = el[jj], sB = el[jj + 6];
      float lA = a2s[sA] + ad;
      float lB = a2s[sB] + ad;
      __half hA = h2[(size_t)sA * 16 + c];
      __half hB = h2[(size_t)sB * 16 + c];
      float eA = EXP2(fmaxf(lA, NEG_SLOPE * lA));
      float eB = EXP2(fmaxf(lB, NEG_SLOPE * lB));
      den += eA + eB;
      acc = fmaf(eA, __half2float(hA), fmaf(eB, __half2float(hB), acc));
    }
    for (; jj < deg; jj += 6) {
      int s = el[jj];
      float l = a2s[s] + ad;
      float ev = EXP2(fmaxf(l, NEG_SLOPE * l));
      den += ev;
      acc = fmaf(ev, __half2float(h2[(size_t)s * 16 + c]), acc);
    }
  }
  acc += __shfl_down(acc, 30, 64);
  den += __shfl_down(den, 30, 64);
  acc += __shfl_down(acc, 10, 64) + __shfl_down(acc, 20, 64);
  den += __shfl_down(den, 10, 64) + __shfl_down(den, 20, 64);
  if (lane < 10) out[(size_t)n * 10 + lane] = acc / den + b2[lane];
}

extern "C" void kernel_launch(void* const* d_in, const int* in_sizes, int n_in,
                              void* d_out, int out_size, void* d_ws, size_t ws_size,
                              hipStream_t stream) {
  const float* x = (const float*)d_in[0];
  const int* ei = (const int*)d_in[1];
  const float* W1 = (const float*)d_in[2];
  const float* as1 = (const float*)d_in[3];
  const float* ad1 = (const float*)d_in[4];
  const float* b1 = (const float*)d_in[5];
  const float* W2 = (const float*)d_in[6];
  const float* as2 = (const float*)d_in[7];
  const float* ad2 = (const float*)d_in[8];
  const float* b2 = (const float*)d_in[9];
  float* out = (float*)d_out;

  const int N = in_sizes[0] / 128;   // 50000
  const int E = in_sizes[1] / 2;     // 800000
  const int ET = E + N;
  const int* srcp = ei;
  const int* dstp = ei + E;

  char* ws = (char*)d_ws;
  size_t off = 0;
  auto alloc = [&](size_t nbytes) {
    char* p = ws + off;
    off += (nbytes + 255) & ~(size_t)255;
    return p;
  };
  __half* h1 = (__half*)alloc((size_t)N * 256 * 2);
  half8* Bpack = (half8*)alloc((size_t)4096 * 16);
  float* a1s = (float*)alloc((size_t)N * 4 * 4);
  float* a1d = (float*)alloc((size_t)N * 4 * 4);
  __half* h2 = (__half*)alloc((size_t)N * 16 * 2);
  float* a2sv = (float*)alloc((size_t)N * 4);
  float* a2dv = (float*)alloc((size_t)N * 4);
  int* deg = (int*)alloc((size_t)N * 4);
  int* excl = (int*)alloc((size_t)N * 4);
  int* bsum = (int*)alloc(256 * 4);
  int* rowptr = (int*)alloc((size_t)(N + 1) * 4);
  int* cursor = (int*)alloc((size_t)N * 4);
  int* elist = (int*)alloc((size_t)ET * 4);

  const int nb = (N + 255) / 256;          // 196
  const int gemmBlocks = (N / 16 + 3) / 4; // 782
  const int histBlocks = 512;

  // L1: pack W1 + zero deg
  prep1<<<16 + nb, 256, 0, stream>>>(W1, Bpack, deg, N);
  // L2: gemm1 (MFMA, fused att dots) || hist_deg
  phase2<<<gemmBlocks + histBlocks, 256, 0, stream>>>(
      x, Bpack, as1, ad1, h1, a1s, a1d, dstp, deg, N, E, gemmBlocks, histBlocks);
  // CSR scan chain (self-loops analytic)
  scan_local<<<nb, 256, 0, stream>>>(deg, excl, bsum, N);
  scan_bsum<<<1, 256, 0, stream>>>(bsum, nb);
  scan_add<<<nb, 256, 0, stream>>>(excl, bsum, rowptr, cursor, elist, N, ET);
  scatter_edges<<<(E + 255) / 256, 256, 0, stream>>>(srcp, dstp, cursor, elist, E);
  // layer 1 aggregate (+ fused GEMM2 / att2)
  agg1_fused<<<(N + 3) / 4, 256, 0, stream>>>(rowptr, elist, h1, a1s, a1d, b1, W2,
                                              as2, ad2, h2, a2sv, a2dv, N);
  // layer 2 aggregate
  agg2_csr<<<(N + 3) / 4, 256, 0, stream>>>(rowptr, elist, h2, a2sv, a2dv, b2, out, N);
}

// Round 9
// 267.523 us; speedup vs baseline: 1.6020x; 1.1060x over previous
//
#include <hip/hip_runtime.h>
#include <hip/hip_fp16.h>
#include <math.h>

#define NEG_SLOPE 0.2f
#define LOG2E 1.44269504088896f

#if __has_builtin(__builtin_amdgcn_exp2f)
#define EXP2(x) __builtin_amdgcn_exp2f(x)
#else
#define EXP2(x) exp2f(x)
#endif

typedef _Float16 half8 __attribute__((ext_vector_type(8)));
typedef float floatx4 __attribute__((ext_vector_type(4)));

// ---------------- L1: pack W1 (blocks 0..15) + zero deg (blocks 16..) --------------
__global__ __launch_bounds__(256) void prep1(const float* __restrict__ W1,
                                             half8* __restrict__ Bpack,
                                             int* __restrict__ deg, int N) {
  if (blockIdx.x < 16) {
    int tid = blockIdx.x * 256 + threadIdx.x;  // 4096 total
    int l = tid & 63;
    int ksnt = tid >> 6;
    int ks = ksnt & 3;
    int nt = ksnt >> 2;
    int col = nt * 16 + (l & 15);
    int krow = ks * 32 + (l >> 4) * 8;
    half8 v;
#pragma unroll
    for (int j = 0; j < 8; j++) v[j] = (_Float16)W1[(krow + j) * 256 + col];
    Bpack[tid] = v;
  } else {
    int i = (blockIdx.x - 16) * 256 + threadIdx.x;
    if (i < N) deg[i] = 0;
  }
}

// ---------------- L2: gemm1 MFMA (+fused att dots) ∥ hist+rank ----------------
__global__ __launch_bounds__(256) void phase2(
    const float* __restrict__ x, const half8* __restrict__ Bpack,
    const float* __restrict__ att_s, const float* __restrict__ att_d,
    __half* __restrict__ h1, float* __restrict__ a1s, float* __restrict__ a1d,
    const int* __restrict__ dst, int* __restrict__ deg, int* __restrict__ rank,
    int N, int E, int gemmBlocks, int histBlocks) {
  if ((int)blockIdx.x >= gemmBlocks) {
    int b = blockIdx.x - gemmBlocks;
    for (int e = b * 256 + threadIdx.x; e < E; e += histBlocks * 256)
      rank[e] = atomicAdd(deg + dst[e], 1);
    return;
  }
  const int wave = threadIdx.x >> 6, lane = threadIdx.x & 63;
  const int quad = lane >> 4, li = lane & 15;
  const int n0 = (blockIdx.x * 4 + wave) * 16;
  if (n0 >= N) return;
  floatx4 acc[16];
#pragma unroll
  for (int t = 0; t < 16; t++) acc[t] = (floatx4){0.f, 0.f, 0.f, 0.f};
  const float* xrow = x + (size_t)(n0 + li) * 128;
#pragma unroll
  for (int ks = 0; ks < 4; ks++) {
    float4 xa = *(const float4*)(xrow + ks * 32 + quad * 8);
    float4 xb = *(const float4*)(xrow + ks * 32 + quad * 8 + 4);
    half8 a;
    a[0] = (_Float16)xa.x; a[1] = (_Float16)xa.y;
    a[2] = (_Float16)xa.z; a[3] = (_Float16)xa.w;
    a[4] = (_Float16)xb.x; a[5] = (_Float16)xb.y;
    a[6] = (_Float16)xb.z; a[7] = (_Float16)xb.w;
#pragma unroll
    for (int nt = 0; nt < 16; nt++) {
      half8 b = Bpack[(nt * 4 + ks) * 64 + lane];
      acc[nt] = __builtin_amdgcn_mfma_f32_16x16x32_f16(a, b, acc[nt], 0, 0, 0);
    }
  }
#pragma unroll
  for (int nt = 0; nt < 16; nt++) {
#pragma unroll
    for (int r = 0; r < 4; r++) {
      h1[(size_t)(n0 + quad * 4 + r) * 256 + nt * 16 + li] = __float2half(acc[nt][r]);
    }
  }
  float as_f[16], ad_f[16];
#pragma unroll
  for (int nt = 0; nt < 16; nt++) {
    as_f[nt] = att_s[nt * 16 + li];
    ad_f[nt] = att_d[nt * 16 + li];
  }
#pragma unroll
  for (int r = 0; r < 4; r++) {
    int node = n0 + quad * 4 + r;
#pragma unroll
    for (int h = 0; h < 4; h++) {
      float vs = 0.f, vd = 0.f;
#pragma unroll
      for (int ntl = 0; ntl < 4; ntl++) {
        int nt = h * 4 + ntl;
        vs = fmaf(acc[nt][r], as_f[nt], vs);
        vd = fmaf(acc[nt][r], ad_f[nt], vd);
      }
#pragma unroll
      for (int off = 8; off > 0; off >>= 1) {
        vs += __shfl_down(vs, off, 16);
        vd += __shfl_down(vd, off, 16);
      }
      if (li == 0) {
        a1s[node * 4 + h] = vs * LOG2E;
        a1d[node * 4 + h] = vd * LOG2E;
      }
    }
  }
}

// ---------------- scan of 4-aligned padded row sizes ----------------
__global__ void scan_local(const int* __restrict__ deg, int* __restrict__ excl,
                           int* __restrict__ bsum, int N) {
  __shared__ int s[256];
  int i = blockIdx.x * 256 + threadIdx.x;
  int v = (i < N) ? ((deg[i] + 1 + 3) & ~3) : 0;  // +1 self-loop, pad start to x4
  s[threadIdx.x] = v;
  __syncthreads();
  for (int off = 1; off < 256; off <<= 1) {
    int t = (threadIdx.x >= off) ? s[threadIdx.x - off] : 0;
    __syncthreads();
    s[threadIdx.x] += t;
    __syncthreads();
  }
  if (i < N) excl[i] = s[threadIdx.x] - v;
  if (threadIdx.x == 255) bsum[blockIdx.x] = s[255];
}

// scan_add2: every block re-scans bsum in LDS (nb <= 256), writes rowptr + self-loop
__global__ void scan_add2(const int* __restrict__ excl, const int* __restrict__ bsum,
                          int* __restrict__ rowptr, int* __restrict__ elist,
                          int N, int nb) {
  __shared__ int s[256];
  int v = (threadIdx.x < nb) ? bsum[threadIdx.x] : 0;
  s[threadIdx.x] = v;
  __syncthreads();
  for (int off = 1; off < 256; off <<= 1) {
    int t = (threadIdx.x >= off) ? s[threadIdx.x - off] : 0;
    __syncthreads();
    s[threadIdx.x] += t;
    __syncthreads();
  }
  __syncthreads();
  int base = (blockIdx.x > 0) ? s[blockIdx.x - 1] : 0;  // exclusive block offset
  int i = blockIdx.x * 256 + threadIdx.x;
  if (i < N) {
    int r = excl[i] + base;
    rowptr[i] = r;
    elist[r] = i;  // self-loop first
  }
}

// ---------------- atomic-free scatter via precomputed rank ----------------
__global__ void scatter2(const int* __restrict__ src, const int* __restrict__ dst,
                         const int* __restrict__ rank, const int* __restrict__ rowptr,
                         int* __restrict__ elist, int E) {
  int e = blockIdx.x * 256 + threadIdx.x;
  if (e >= E) return;
  elist[rowptr[dst[e]] + 1 + rank[e]] = src[e];
}

// ---------------- agg1: wave-per-node CSR aggregate (unroll-8, int4 el loads),
// fast-exp softmax + bias1 + ELU + GEMM2 (W2 in LDS, stride 41) + att2 dots --------
__global__ __launch_bounds__(256) void agg1_fused(
    const int* __restrict__ rowptr, const int* __restrict__ degp,
    const int* __restrict__ elist, const __half* __restrict__ h1,
    const float* __restrict__ a1s, const float* __restrict__ a1d,
    const float* __restrict__ b1, const float* __restrict__ W2,
    const float* __restrict__ as2, const float* __restrict__ ad2,
    __half* __restrict__ h2, float* __restrict__ a2s, float* __restrict__ a2d,
    int N) {
  __shared__ float w2s[64 * 41];  // lane-stride 41 -> conflict-free
  const int t = threadIdx.x;
  for (int i = t; i < 2560; i += 256) {
    int ch = i / 10, jj = i - ch * 10;
    w2s[(ch >> 2) * 41 + (ch & 3) * 10 + jj] = W2[i];
  }
  __syncthreads();

  const int wave = t >> 6, lane = t & 63;
  const int n = blockIdx.x * 4 + wave;
  if (n >= N) return;
  const int row = rowptr[n];       // 4-aligned
  const int deg = degp[n] + 1;     // + self-loop
  const int* el = elist + row;
  const int hidx = lane >> 4;
  const float adh = a1d[n * 4 + hidx];  // pre-scaled by log2e

  float den = 0.f;
  float acc0 = 0.f, acc1 = 0.f, acc2 = 0.f, acc3 = 0.f;
  int j = 0;
  for (; j + 8 <= deg; j += 8) {
    int4 eA = *(const int4*)(el + j);
    int4 eB = *(const int4*)(el + j + 4);
    int ss[8] = {eA.x, eA.y, eA.z, eA.w, eB.x, eB.y, eB.z, eB.w};
    float lv[8];
    uint2 uv[8];
#pragma unroll
    for (int u = 0; u < 8; u++) {
      lv[u] = a1s[ss[u] * 4 + hidx];
      uv[u] = *(const uint2*)(h1 + (size_t)ss[u] * 256 + lane * 4);
    }
#pragma unroll
    for (int u = 0; u < 8; u++) {
      float l = lv[u] + adh;
      float e = EXP2(fmaxf(l, NEG_SLOPE * l));
      den += e;
      float2 a = __half22float2(*(const __half2*)&uv[u].x);
      float2 b = __half22float2(*(const __half2*)&uv[u].y);
      acc0 = fmaf(e, a.x, acc0); acc1 = fmaf(e, a.y, acc1);
      acc2 = fmaf(e, b.x, acc2); acc3 = fmaf(e, b.y, acc3);
    }
  }
  for (; j + 4 <= deg; j += 4) {
    int4 eA = *(const int4*)(el + j);
    int ss[4] = {eA.x, eA.y, eA.z, eA.w};
    float lv[4];
    uint2 uv[4];
#pragma unroll
    for (int u = 0; u < 4; u++) {
      lv[u] = a1s[ss[u] * 4 + hidx];
      uv[u] = *(const uint2*)(h1 + (size_t)ss[u] * 256 + lane * 4);
    }
#pragma unroll
    for (int u = 0; u < 4; u++) {
      float l = lv[u] + adh;
      float e = EXP2(fmaxf(l, NEG_SLOPE * l));
      den += e;
      float2 a = __half22float2(*(const __half2*)&uv[u].x);
      float2 b = __half22float2(*(const __half2*)&uv[u].y);
      acc0 = fmaf(e, a.x, acc0); acc1 = fmaf(e, a.y, acc1);
      acc2 = fmaf(e, b.x, acc2); acc3 = fmaf(e, b.y, acc3);
    }
  }
  for (; j < deg; j++) {
    int s0 = el[j];
    float l0 = a1s[s0 * 4 + hidx] + adh;
    uint2 u0 = *(const uint2*)(h1 + (size_t)s0 * 256 + lane * 4);
    float e0 = EXP2(fmaxf(l0, NEG_SLOPE * l0));
    den += e0;
    float2 a = __half22float2(*(const __half2*)&u0.x);
    float2 b = __half22float2(*(const __half2*)&u0.y);
    acc0 = fmaf(e0, a.x, acc0); acc1 = fmaf(e0, a.y, acc1);
    acc2 = fmaf(e0, b.x, acc2); acc3 = fmaf(e0, b.y, acc3);
  }

  float inv = 1.0f / den;
  float4 bb = *(const float4*)(b1 + lane * 4);
  float c0 = fmaf(acc0, inv, bb.x);
  float c1 = fmaf(acc1, inv, bb.y);
  float c2 = fmaf(acc2, inv, bb.z);
  float c3 = fmaf(acc3, inv, bb.w);
  c0 = c0 > 0.f ? c0 : expm1f(c0);
  c1 = c1 > 0.f ? c1 : expm1f(c1);
  c2 = c2 > 0.f ? c2 : expm1f(c2);
  c3 = c3 > 0.f ? c3 : expm1f(c3);
  const float* w0 = w2s + lane * 41;
  float p[10];
#pragma unroll
  for (int jj = 0; jj < 10; jj++)
    p[jj] = fmaf(c0, w0[jj], fmaf(c1, w0[10 + jj], fmaf(c2, w0[20 + jj], c3 * w0[30 + jj])));
#pragma unroll
  for (int jj = 0; jj < 10; jj++) {
#pragma unroll
    for (int off = 32; off > 0; off >>= 1) p[jj] += __shfl_down(p[jj], off, 64);
  }
  if (lane == 0) {
    float ds = 0.f, dd = 0.f;
#pragma unroll
    for (int jj = 0; jj < 10; jj++) {
      h2[(size_t)n * 16 + jj] = __float2half(p[jj]);
      ds = fmaf(p[jj], as2[jj], ds);
      dd = fmaf(p[jj], ad2[jj], dd);
    }
    a2s[n] = ds * LOG2E;
    a2d[n] = dd * LOG2E;
  }
}

// ---------------- agg2: wave-per-node layer-2 aggregate, fast-exp, unroll-2 --------
__global__ __launch_bounds__(256) void agg2_csr(
    const int* __restrict__ rowptr, const int* __restrict__ degp,
    const int* __restrict__ elist, const __half* __restrict__ h2,
    const float* __restrict__ a2s, const float* __restrict__ a2d,
    const float* __restrict__ b2, float* __restrict__ out, int N) {
  int wave = threadIdx.x >> 6, lane = threadIdx.x & 63;
  int n = blockIdx.x * 4 + wave;
  if (n >= N) return;
  int row = rowptr[n];
  int deg = degp[n] + 1;
  const int* el = elist + row;
  float ad = a2d[n];  // pre-scaled
  int g = lane / 10;  // 0..5 active, lanes 60-63 idle
  int c = lane - g * 10;
  float den = 0.f, acc = 0.f;
  if (g < 6) {
    int jj = g;
    for (; jj + 6 < deg; jj += 12) {
      int sA = el[jj], sB = el[jj + 6];
      float lA = a2s[sA] + ad;
      float lB = a2s[sB] + ad;
      __half hA = h2[(size_t)sA * 16 + c];
      __half hB = h2[(size_t)sB * 16 + c];
      float eA = EXP2(fmaxf(lA, NEG_SLOPE * lA));
      float eB = EXP2(fmaxf(lB, NEG_SLOPE * lB));
      den += eA + eB;
      acc = fmaf(eA, __half2float(hA), fmaf(eB, __half2float(hB), acc));
    }
    for (; jj < deg; jj += 6) {
      int s = el[jj];
      float l = a2s[s] + ad;
      float ev = EXP2(fmaxf(l, NEG_SLOPE * l));
      den += ev;
      acc = fmaf(ev, __half2float(h2[(size_t)s * 16 + c]), acc);
    }
  }
  acc += __shfl_down(acc, 30, 64);
  den += __shfl_down(den, 30, 64);
  acc += __shfl_down(acc, 10, 64) + __shfl_down(acc, 20, 64);
  den += __shfl_down(den, 10, 64) + __shfl_down(den, 20, 64);
  if (lane < 10) out[(size_t)n * 10 + lane] = acc / den + b2[lane];
}

extern "C" void kernel_launch(void* const* d_in, const int* in_sizes, int n_in,
                              void* d_out, int out_size, void* d_ws, size_t ws_size,
                              hipStream_t stream) {
  const float* x = (const float*)d_in[0];
  const int* ei = (const int*)d_in[1];
  const float* W1 = (const float*)d_in[2];
  const float* as1 = (const float*)d_in[3];
  const float* ad1 = (const float*)d_in[4];
  const float* b1 = (const float*)d_in[5];
  const float* W2 = (const float*)d_in[6];
  const float* as2 = (const float*)d_in[7];
  const float* ad2 = (const float*)d_in[8];
  const float* b2 = (const float*)d_in[9];
  float* out = (float*)d_out;

  const int N = in_sizes[0] / 128;   // 50000
  const int E = in_sizes[1] / 2;     // 800000
  const int* srcp = ei;
  const int* dstp = ei + E;

  char* ws = (char*)d_ws;
  size_t off = 0;
  auto alloc = [&](size_t nbytes) {
    char* p = ws + off;
    off += (nbytes + 255) & ~(size_t)255;
    return p;
  };
  __half* h1 = (__half*)alloc((size_t)N * 256 * 2);
  half8* Bpack = (half8*)alloc((size_t)4096 * 16);
  float* a1s = (float*)alloc((size_t)N * 4 * 4);
  float* a1d = (float*)alloc((size_t)N * 4 * 4);
  __half* h2 = (__half*)alloc((size_t)N * 16 * 2);
  float* a2sv = (float*)alloc((size_t)N * 4);
  float* a2dv = (float*)alloc((size_t)N * 4);
  int* deg = (int*)alloc((size_t)N * 4);
  int* excl = (int*)alloc((size_t)N * 4);
  int* bsum = (int*)alloc(256 * 4);
  int* rowptr = (int*)alloc((size_t)(N + 1) * 4);
  int* rank = (int*)alloc((size_t)E * 4);
  int* elist = (int*)alloc((size_t)(E + 4 * (size_t)N) * 4);  // padded rows

  const int nb = (N + 255) / 256;          // 196
  const int gemmBlocks = (N / 16 + 3) / 4; // 782
  const int histBlocks = 512;

  // L1: pack W1 + zero deg
  prep1<<<16 + nb, 256, 0, stream>>>(W1, Bpack, deg, N);
  // L2: gemm1 (MFMA, fused att dots) || hist+rank
  phase2<<<gemmBlocks + histBlocks, 256, 0, stream>>>(
      x, Bpack, as1, ad1, h1, a1s, a1d, dstp, deg, rank, N, E, gemmBlocks, histBlocks);
  // CSR: scan padded sizes, rowptr + self-loops, atomic-free scatter
  scan_local<<<nb, 256, 0, stream>>>(deg, excl, bsum, N);
  scan_add2<<<nb, 256, 0, stream>>>(excl, bsum, rowptr, elist, N, nb);
  scatter2<<<(E + 255) / 256, 256, 0, stream>>>(srcp, dstp, rank, rowptr, elist, E);
  // layer 1 aggregate (+ fused GEMM2 / att2)
  agg1_fused<<<(N + 3) / 4, 256, 0, stream>>>(rowptr, deg, elist, h1, a1s, a1d, b1,
                                              W2, as2, ad2, h2, a2sv, a2dv, N);
  // layer 2 aggregate
  agg2_csr<<<(N + 3) / 4, 256, 0, stream>>>(rowptr, deg, elist, h2, a2sv, a2dv, b2,
                                            out, N);
}

// Round 10
// 256.662 us; speedup vs baseline: 1.6698x; 1.0423x over previous
//
#include <hip/hip_runtime.h>
#include <hip/hip_fp16.h>
#include <math.h>

#define NEG_SLOPE 0.2f
#define LOG2E 1.44269504088896f

#if __has_builtin(__builtin_amdgcn_exp2f)
#define EXP2(x) __builtin_amdgcn_exp2f(x)
#else
#define EXP2(x) exp2f(x)
#endif

typedef _Float16 half8 __attribute__((ext_vector_type(8)));
typedef float floatx4 __attribute__((ext_vector_type(4)));

// ---------------- L1: pack W1 (blocks 0..15) + zero deg (blocks 16..) --------------
__global__ __launch_bounds__(256) void prep1(const float* __restrict__ W1,
                                             half8* __restrict__ Bpack,
                                             int* __restrict__ deg, int N) {
  if (blockIdx.x < 16) {
    int tid = blockIdx.x * 256 + threadIdx.x;  // 4096 total
    int l = tid & 63;
    int ksnt = tid >> 6;
    int ks = ksnt & 3;
    int nt = ksnt >> 2;
    int col = nt * 16 + (l & 15);
    int krow = ks * 32 + (l >> 4) * 8;
    half8 v;
#pragma unroll
    for (int j = 0; j < 8; j++) v[j] = (_Float16)W1[(krow + j) * 256 + col];
    Bpack[tid] = v;
  } else {
    int i = (blockIdx.x - 16) * 256 + threadIdx.x;
    if (i < N) deg[i] = 0;
  }
}

// ---------------- L2: gemm1 MFMA -> int8 h1 (per-row scale) + att dots ∥ hist+rank --
__global__ __launch_bounds__(256) void phase2(
    const float* __restrict__ x, const half8* __restrict__ Bpack,
    const float* __restrict__ att_s, const float* __restrict__ att_d,
    unsigned char* __restrict__ h1q, float* __restrict__ hscale,
    float* __restrict__ a1s, float* __restrict__ a1d,
    const int* __restrict__ dst, int* __restrict__ deg, int* __restrict__ rank,
    int N, int E, int gemmBlocks, int histBlocks) {
  if ((int)blockIdx.x >= gemmBlocks) {
    int b = blockIdx.x - gemmBlocks;
    for (int e = b * 256 + threadIdx.x; e < E; e += histBlocks * 256)
      rank[e] = atomicAdd(deg + dst[e], 1);
    return;
  }
  const int wave = threadIdx.x >> 6, lane = threadIdx.x & 63;
  const int quad = lane >> 4, li = lane & 15;
  const int n0 = (blockIdx.x * 4 + wave) * 16;
  if (n0 >= N) return;
  floatx4 acc[16];
#pragma unroll
  for (int t = 0; t < 16; t++) acc[t] = (floatx4){0.f, 0.f, 0.f, 0.f};
  const float* xrow = x + (size_t)(n0 + li) * 128;
#pragma unroll
  for (int ks = 0; ks < 4; ks++) {
    float4 xa = *(const float4*)(xrow + ks * 32 + quad * 8);
    float4 xb = *(const float4*)(xrow + ks * 32 + quad * 8 + 4);
    half8 a;
    a[0] = (_Float16)xa.x; a[1] = (_Float16)xa.y;
    a[2] = (_Float16)xa.z; a[3] = (_Float16)xa.w;
    a[4] = (_Float16)xb.x; a[5] = (_Float16)xb.y;
    a[6] = (_Float16)xb.z; a[7] = (_Float16)xb.w;
#pragma unroll
    for (int nt = 0; nt < 16; nt++) {
      half8 b = Bpack[(nt * 4 + ks) * 64 + lane];
      acc[nt] = __builtin_amdgcn_mfma_f32_16x16x32_f16(a, b, acc[nt], 0, 0, 0);
    }
  }
  // int8 quantize: row (m = quad*4 + r) absmax over 256 ch -> scale
#pragma unroll
  for (int r = 0; r < 4; r++) {
    float m = 0.f;
#pragma unroll
    for (int nt = 0; nt < 16; nt++) m = fmaxf(m, fabsf(acc[nt][r]));
#pragma unroll
    for (int off = 8; off > 0; off >>= 1) m = fmaxf(m, __shfl_xor(m, off, 16));
    m = fmaxf(m, 1e-8f);
    float inv = 127.0f / m;
    int node = n0 + quad * 4 + r;
    if (li == 0) hscale[node] = m * (1.0f / 127.0f);
#pragma unroll
    for (int nt = 0; nt < 16; nt++) {
      h1q[(size_t)node * 256 + nt * 16 + li] =
          (unsigned char)(int)(fmaf(acc[nt][r], inv, 128.5f));
    }
  }
  // fused attention dots (fp32 acc, pre-quantization)
  float as_f[16], ad_f[16];
#pragma unroll
  for (int nt = 0; nt < 16; nt++) {
    as_f[nt] = att_s[nt * 16 + li];
    ad_f[nt] = att_d[nt * 16 + li];
  }
#pragma unroll
  for (int r = 0; r < 4; r++) {
    int node = n0 + quad * 4 + r;
#pragma unroll
    for (int h = 0; h < 4; h++) {
      float vs = 0.f, vd = 0.f;
#pragma unroll
      for (int ntl = 0; ntl < 4; ntl++) {
        int nt = h * 4 + ntl;
        vs = fmaf(acc[nt][r], as_f[nt], vs);
        vd = fmaf(acc[nt][r], ad_f[nt], vd);
      }
#pragma unroll
      for (int off = 8; off > 0; off >>= 1) {
        vs += __shfl_down(vs, off, 16);
        vd += __shfl_down(vd, off, 16);
      }
      if (li == 0) {
        a1s[node * 4 + h] = vs * LOG2E;
        a1d[node * 4 + h] = vd * LOG2E;
      }
    }
  }
}

// ---------------- CSR scan chain (unpadded rows) ----------------
__global__ void scan_local(const int* __restrict__ deg, int* __restrict__ excl,
                           int* __restrict__ bsum, int N) {
  __shared__ int s[256];
  int i = blockIdx.x * 256 + threadIdx.x;
  int v = (i < N) ? deg[i] + 1 : 0;  // +1 self-loop
  s[threadIdx.x] = v;
  __syncthreads();
  for (int off = 1; off < 256; off <<= 1) {
    int t = (threadIdx.x >= off) ? s[threadIdx.x - off] : 0;
    __syncthreads();
    s[threadIdx.x] += t;
    __syncthreads();
  }
  if (i < N) excl[i] = s[threadIdx.x] - v;
  if (threadIdx.x == 255) bsum[blockIdx.x] = s[255];
}

// scan_add2: every block re-scans bsum in LDS (nb <= 256), writes rowptr + self-loop
__global__ void scan_add2(const int* __restrict__ excl, const int* __restrict__ bsum,
                          int* __restrict__ rowptr, int* __restrict__ elist,
                          int N, int nb) {
  __shared__ int s[256];
  int v = (threadIdx.x < nb) ? bsum[threadIdx.x] : 0;
  s[threadIdx.x] = v;
  __syncthreads();
  for (int off = 1; off < 256; off <<= 1) {
    int t = (threadIdx.x >= off) ? s[threadIdx.x - off] : 0;
    __syncthreads();
    s[threadIdx.x] += t;
    __syncthreads();
  }
  __syncthreads();
  int base = (blockIdx.x > 0) ? s[blockIdx.x - 1] : 0;  // exclusive block offset
  int i = blockIdx.x * 256 + threadIdx.x;
  if (i < N) {
    int r = excl[i] + base;
    rowptr[i] = r;
    elist[r] = i;  // self-loop first
  }
  if (blockIdx.x == 0 && threadIdx.x == 0) rowptr[N] = s[nb - 1];  // total = ET
}

// ---------------- atomic-free scatter via precomputed rank ----------------
__global__ void scatter2(const int* __restrict__ src, const int* __restrict__ dst,
                         const int* __restrict__ rank, const int* __restrict__ rowptr,
                         int* __restrict__ elist, int E) {
  int e = blockIdx.x * 256 + threadIdx.x;
  if (e >= E) return;
  elist[rowptr[dst[e]] + 1 + rank[e]] = src[e];
}

// ---------------- agg1: wave-per-node CSR aggregate over int8 h1 (unroll-8),
// fast-exp softmax + bias1 + ELU + GEMM2 (W2 in LDS, stride 41) + att2 dots --------
__global__ __launch_bounds__(256) void agg1_fused(
    const int* __restrict__ rowptr, const int* __restrict__ elist,
    const unsigned char* __restrict__ h1q, const float* __restrict__ hscale,
    const float* __restrict__ a1s, const float* __restrict__ a1d,
    const float* __restrict__ b1, const float* __restrict__ W2,
    const float* __restrict__ as2, const float* __restrict__ ad2,
    __half* __restrict__ h2, float* __restrict__ a2s, float* __restrict__ a2d,
    int N) {
  __shared__ float w2s[64 * 41];  // lane-stride 41 -> conflict-free
  const int t = threadIdx.x;
  for (int i = t; i < 2560; i += 256) {
    int ch = i / 10, jj = i - ch * 10;
    w2s[(ch >> 2) * 41 + (ch & 3) * 10 + jj] = W2[i];
  }
  __syncthreads();

  const int wave = t >> 6, lane = t & 63;
  const int n = blockIdx.x * 4 + wave;
  if (n >= N) return;
  const int row = rowptr[n];
  const int deg = rowptr[n + 1] - row;
  const int* el = elist + row;
  const int hidx = lane >> 4;
  const float adh = a1d[n * 4 + hidx];  // pre-scaled by log2e

  float den = 0.f, T = 0.f;
  float acc0 = 0.f, acc1 = 0.f, acc2 = 0.f, acc3 = 0.f;
  int j = 0;
  for (; j + 8 <= deg; j += 8) {
    int ss[8];
#pragma unroll
    for (int u = 0; u < 8; u++) ss[u] = el[j + u];
    float lv[8], sc[8];
    unsigned int qv[8];
#pragma unroll
    for (int u = 0; u < 8; u++) {
      lv[u] = a1s[ss[u] * 4 + hidx];
      sc[u] = hscale[ss[u]];
      qv[u] = *(const unsigned int*)(h1q + (size_t)ss[u] * 256 + lane * 4);
    }
#pragma unroll
    for (int u = 0; u < 8; u++) {
      float l = lv[u] + adh;
      float e = EXP2(fmaxf(l, NEG_SLOPE * l));
      den += e;
      float se = e * sc[u];
      T += se;
      acc0 = fmaf((float)(qv[u] & 0xffu), se, acc0);
      acc1 = fmaf((float)((qv[u] >> 8) & 0xffu), se, acc1);
      acc2 = fmaf((float)((qv[u] >> 16) & 0xffu), se, acc2);
      acc3 = fmaf((float)(qv[u] >> 24), se, acc3);
    }
  }
  for (; j + 4 <= deg; j += 4) {
    int ss[4];
#pragma unroll
    for (int u = 0; u < 4; u++) ss[u] = el[j + u];
    float lv[4], sc[4];
    unsigned int qv[4];
#pragma unroll
    for (int u = 0; u < 4; u++) {
      lv[u] = a1s[ss[u] * 4 + hidx];
      sc[u] = hscale[ss[u]];
      qv[u] = *(const unsigned int*)(h1q + (size_t)ss[u] * 256 + lane * 4);
    }
#pragma unroll
    for (int u = 0; u < 4; u++) {
      float l = lv[u] + adh;
      float e = EXP2(fmaxf(l, NEG_SLOPE * l));
      den += e;
      float se = e * sc[u];
      T += se;
      acc0 = fmaf((float)(qv[u] & 0xffu), se, acc0);
      acc1 = fmaf((float)((qv[u] >> 8) & 0xffu), se, acc1);
      acc2 = fmaf((float)((qv[u] >> 16) & 0xffu), se, acc2);
      acc3 = fmaf((float)(qv[u] >> 24), se, acc3);
    }
  }
  for (; j < deg; j++) {
    int s0 = el[j];
    float l0 = a1s[s0 * 4 + hidx] + adh;
    float sc0 = hscale[s0];
    unsigned int q0 = *(const unsigned int*)(h1q + (size_t)s0 * 256 + lane * 4);
    float e0 = EXP2(fmaxf(l0, NEG_SLOPE * l0));
    den += e0;
    float se = e0 * sc0;
    T += se;
    acc0 = fmaf((float)(q0 & 0xffu), se, acc0);
    acc1 = fmaf((float)((q0 >> 8) & 0xffu), se, acc1);
    acc2 = fmaf((float)((q0 >> 16) & 0xffu), se, acc2);
    acc3 = fmaf((float)(q0 >> 24), se, acc3);
  }

  // undo the +128 offset: sum(se*(q-128)) = sum(se*q) - 128*sum(se)
  float corr = 128.0f * T;
  acc0 -= corr; acc1 -= corr; acc2 -= corr; acc3 -= corr;

  float inv = 1.0f / den;
  float4 bb = *(const float4*)(b1 + lane * 4);
  float c0 = fmaf(acc0, inv, bb.x);
  float c1 = fmaf(acc1, inv, bb.y);
  float c2 = fmaf(acc2, inv, bb.z);
  float c3 = fmaf(acc3, inv, bb.w);
  c0 = c0 > 0.f ? c0 : expm1f(c0);
  c1 = c1 > 0.f ? c1 : expm1f(c1);
  c2 = c2 > 0.f ? c2 : expm1f(c2);
  c3 = c3 > 0.f ? c3 : expm1f(c3);
  const float* w0 = w2s + lane * 41;
  float p[10];
#pragma unroll
  for (int jj = 0; jj < 10; jj++)
    p[jj] = fmaf(c0, w0[jj], fmaf(c1, w0[10 + jj], fmaf(c2, w0[20 + jj], c3 * w0[30 + jj])));
#pragma unroll
  for (int jj = 0; jj < 10; jj++) {
#pragma unroll
    for (int off = 32; off > 0; off >>= 1) p[jj] += __shfl_down(p[jj], off, 64);
  }
  if (lane == 0) {
    float ds = 0.f, dd = 0.f;
#pragma unroll
    for (int jj = 0; jj < 10; jj++) {
      h2[(size_t)n * 16 + jj] = __float2half(p[jj]);
      ds = fmaf(p[jj], as2[jj], ds);
      dd = fmaf(p[jj], ad2[jj], dd);
    }
    a2s[n] = ds * LOG2E;
    a2d[n] = dd * LOG2E;
  }
}

// ---------------- agg2: wave-per-node layer-2 aggregate, fast-exp, unroll-2 --------
__global__ __launch_bounds__(256) void agg2_csr(
    const int* __restrict__ rowptr, const int* __restrict__ elist,
    const __half* __restrict__ h2, const float* __restrict__ a2s,
    const float* __restrict__ a2d, const float* __restrict__ b2,
    float* __restrict__ out, int N) {
  int wave = threadIdx.x >> 6, lane = threadIdx.x & 63;
  int n = blockIdx.x * 4 + wave;
  if (n >= N) return;
  int row = rowptr[n];
  int deg = rowptr[n + 1] - row;
  const int* el = elist + row;
  float ad = a2d[n];  // pre-scaled
  int g = lane / 10;  // 0..5 active, lanes 60-63 idle
  int c = lane - g * 10;
  float den = 0.f, acc = 0.f;
  if (g < 6) {
    int jj = g;
    for (; jj + 6 < deg; jj += 12) {
      int sA = el[jj], sB = el[jj + 6];
      float lA = a2s[sA] + ad;
      float lB = a2s[sB] + ad;
      __half hA = h2[(size_t)sA * 16 + c];
      __half hB = h2[(size_t)sB * 16 + c];
      float eA = EXP2(fmaxf(lA, NEG_SLOPE * lA));
      float eB = EXP2(fmaxf(lB, NEG_SLOPE * lB));
      den += eA + eB;
      acc = fmaf(eA, __half2float(hA), fmaf(eB, __half2float(hB), acc));
    }
    for (; jj < deg; jj += 6) {
      int s = el[jj];
      float l = a2s[s] + ad;
      float ev = EXP2(fmaxf(l, NEG_SLOPE * l));
      den += ev;
      acc = fmaf(ev, __half2float(h2[(size_t)s * 16 + c]), acc);
    }
  }
  acc += __shfl_down(acc, 30, 64);
  den += __shfl_down(den, 30, 64);
  acc += __shfl_down(acc, 10, 64) + __shfl_down(acc, 20, 64);
  den += __shfl_down(den, 10, 64) + __shfl_down(den, 20, 64);
  if (lane < 10) out[(size_t)n * 10 + lane] = acc / den + b2[lane];
}

extern "C" void kernel_launch(void* const* d_in, const int* in_sizes, int n_in,
                              void* d_out, int out_size, void* d_ws, size_t ws_size,
                              hipStream_t stream) {
  const float* x = (const float*)d_in[0];
  const int* ei = (const int*)d_in[1];
  const float* W1 = (const float*)d_in[2];
  const float* as1 = (const float*)d_in[3];
  const float* ad1 = (const float*)d_in[4];
  const float* b1 = (const float*)d_in[5];
  const float* W2 = (const float*)d_in[6];
  const float* as2 = (const float*)d_in[7];
  const float* ad2 = (const float*)d_in[8];
  const float* b2 = (const float*)d_in[9];
  float* out = (float*)d_out;

  const int N = in_sizes[0] / 128;   // 50000
  const int E = in_sizes[1] / 2;     // 800000
  const int* srcp = ei;
  const int* dstp = ei + E;

  char* ws = (char*)d_ws;
  size_t off = 0;
  auto alloc = [&](size_t nbytes) {
    char* p = ws + off;
    off += (nbytes + 255) & ~(size_t)255;
    return p;
  };
  unsigned char* h1q = (unsigned char*)alloc((size_t)N * 256);
  float* hscale = (float*)alloc((size_t)N * 4);
  half8* Bpack = (half8*)alloc((size_t)4096 * 16);
  float* a1s = (float*)alloc((size_t)N * 4 * 4);
  float* a1d = (float*)alloc((size_t)N * 4 * 4);
  __half* h2 = (__half*)alloc((size_t)N * 16 * 2);
  float* a2sv = (float*)alloc((size_t)N * 4);
  float* a2dv = (float*)alloc((size_t)N * 4);
  int* deg = (int*)alloc((size_t)N * 4);
  int* excl = (int*)alloc((size_t)N * 4);
  int* bsum = (int*)alloc(256 * 4);
  int* rowptr = (int*)alloc((size_t)(N + 1) * 4);
  int* rank = (int*)alloc((size_t)E * 4);
  int* elist = (int*)alloc((size_t)(E + (size_t)N) * 4);

  const int nb = (N + 255) / 256;          // 196
  const int gemmBlocks = (N / 16 + 3) / 4; // 782
  const int histBlocks = 512;

  // L1: pack W1 + zero deg
  prep1<<<16 + nb, 256, 0, stream>>>(W1, Bpack, deg, N);
  // L2: gemm1 (MFMA -> int8 + scales, fused att dots) || hist+rank
  phase2<<<gemmBlocks + histBlocks, 256, 0, stream>>>(
      x, Bpack, as1, ad1, h1q, hscale, a1s, a1d, dstp, deg, rank, N, E,
      gemmBlocks, histBlocks);
  // CSR: scan, rowptr + self-loops, atomic-free scatter
  scan_local<<<nb, 256, 0, stream>>>(deg, excl, bsum, N);
  scan_add2<<<nb, 256, 0, stream>>>(excl, bsum, rowptr, elist, N, nb);
  scatter2<<<(E + 255) / 256, 256, 0, stream>>>(srcp, dstp, rank, rowptr, elist, E);
  // layer 1 aggregate (+ fused GEMM2 / att2)
  agg1_fused<<<(N + 3) / 4, 256, 0, stream>>>(rowptr, elist, h1q, hscale, a1s, a1d,
                                              b1, W2, as2, ad2, h2, a2sv, a2dv, N);
  // layer 2 aggregate
  agg2_csr<<<(N + 3) / 4, 256, 0, stream>>>(rowptr, elist, h2, a2sv, a2dv, b2, out, N);
}